// Round 6
// baseline (3192.218 us; speedup 1.0000x reference)
//
#include <hip/hip_runtime.h>

using u16 = unsigned short;
using u32 = unsigned int;

typedef _Float16 f16x2 __attribute__((ext_vector_type(2)));
typedef _Float16 f16x8 __attribute__((ext_vector_type(8)));
typedef float    f32x4 __attribute__((ext_vector_type(4)));

__device__ __forceinline__ u16 f16bits(float x) {
  union { _Float16 h; u16 u; } r; r.h = (_Float16)x; return r.u;
}
__device__ __forceinline__ float h2f(u16 v) {
  union { u16 u; _Float16 h; } r; r.u = v; return (float)r.h;
}
__device__ __forceinline__ u32 pack2(float a, float b) {
  union { f16x2 h; u32 u; } r; r.h.x = (_Float16)a; r.h.y = (_Float16)b; return r.u;
}
__device__ __forceinline__ float fdot2a(u32 a, u32 b, float c) {
  union { u32 u; f16x2 h; } ua, ub; ua.u = a; ub.u = b;
#if __has_builtin(__builtin_amdgcn_fdot2)
  return __builtin_amdgcn_fdot2(ua.h, ub.h, c, false);
#else
  return c + (float)ua.h.x * (float)ub.h.x + (float)ua.h.y * (float)ub.h.y;
#endif
}
__device__ __forceinline__ float sigmoidf_(float x) { return 1.0f / (1.0f + __expf(-x)); }
__device__ __forceinline__ float tanhf_(float x)    { return 1.0f - 2.0f / (__expf(2.0f * x) + 1.0f); }

__device__ __forceinline__ f16x8 lds16(const u16* p) {
  union { uint4 u; f16x8 h; } r; r.u = *(const uint4*)p; return r.h;
}

// Cross-quarter reduce on the VALU pipe (permlane swaps), not LDS (bpermute).
__device__ __forceinline__ float qreduce(float a) {
#if __has_builtin(__builtin_amdgcn_permlane16_swap) && __has_builtin(__builtin_amdgcn_permlane32_swap)
  typedef unsigned uv2 __attribute__((ext_vector_type(2)));
  union { float f; unsigned u; } x, p, q;
  x.f = a;
  uv2 r1 = __builtin_amdgcn_permlane16_swap(x.u, x.u, false, false);
  p.u = r1[0]; q.u = r1[1];
  float s = p.f + q.f;
  x.f = s;
  uv2 r2 = __builtin_amdgcn_permlane32_swap(x.u, x.u, false, false);
  p.u = r2[0]; q.u = r2[1];
  return p.f + q.f;
#else
  a += __shfl_xor(a, 16);
  a += __shfl_xor(a, 32);
  return a;
#endif
}

// ---------------- prep: build f16 weight layouts + zero state ----------------
// WxT[n][k]   : [1024][256] f16, transposed input-proj weights
// Whpp[i4][t] : [64][512] uint4 — per-(rec-)thread gathered W_h pair groups.
//   rec thread t (of 512): w=t>>6, l=t&63, q=l>>4, us=w*16+(l&15);
//   i4 = (uu*4+g)*8+pp; unit=(us*2+uu); element e = f16x2 pair kk=q*32+pp*4+e
//   of column `unit` of gate-g W_h.
__global__ void lstm_prep(const float* __restrict__ Wxi, const float* __restrict__ Wxf,
                          const float* __restrict__ Wxg, const float* __restrict__ Wxo,
                          const float* __restrict__ Whi, const float* __restrict__ Whf,
                          const float* __restrict__ Whg, const float* __restrict__ Who,
                          u16* __restrict__ WxT, u32* __restrict__ Whpp,
                          u32* __restrict__ h16s, float* __restrict__ c_s) {
  int idx = blockIdx.x * 256 + threadIdx.x;
  if (idx < 262144) {                       // WxT
    int n = idx >> 8, k = idx & 255;
    int g = n >> 8;
    const float* W = (g == 0) ? Wxi : (g == 1) ? Wxf : (g == 2) ? Wxg : Wxo;
    WxT[idx] = f16bits(W[k * 256 + (n & 255)]);
  } else if (idx < 262144 + 131072) {       // Whpp (u32-granular writes)
    int i2 = idx - 262144;
    int e = i2 & 3, tmp = i2 >> 2;
    int t = tmp & 511, i4 = tmp >> 9;       // t in [0,512), i4 in [0,64)
    int pp = i4 & 7, ug = i4 >> 3;          // ug = uu*4+g
    int g = ug & 3, uu = ug >> 2;
    int w = t >> 6, l = t & 63, q = l >> 4;
    int unit = (w * 16 + (l & 15)) * 2 + uu;
    int kk = q * 32 + pp * 4 + e;
    const float* W = (g == 0) ? Whi : (g == 1) ? Whf : (g == 2) ? Whg : Who;
    u32 lo = f16bits(W[(2 * kk) * 256 + unit]);
    u32 hi = f16bits(W[(2 * kk + 1) * 256 + unit]);
    Whpp[i2] = lo | (hi << 16);
  } else if (idx < 262144 + 131072 + 16384) {
    h16s[idx - 393216] = 0u;
  } else if (idx < 262144 + 131072 + 16384 + 32768) {
    c_s[idx - 409600] = 0.0f;
  }
}

// ---------------- standalone input-projection GEMM (chunk 0 prologue) --------
// Writes PERMUTED gate layout: gates[m][ (n&255)*4 + (n>>8) ].
__global__ __launch_bounds__(256) void proj_gemm(
    const float* __restrict__ x, const u16* __restrict__ WxT,
    u16* __restrict__ gates, const float* __restrict__ bi,
    const float* __restrict__ bf, const float* __restrict__ bg,
    const float* __restrict__ bo, int t0, int tcShift) {
  __shared__ u16 Al[128 * 72];
  __shared__ u16 Bl[128 * 72];
  const int tid = threadIdx.x;
  const int lane = tid & 63, wv = tid >> 6;
  const int wr = wv >> 1, wc = wv & 1;
  const int m0 = blockIdx.x * 128, n0 = blockIdx.y * 128;
  const int tcMask = (1 << tcShift) - 1;
  f32x4 acc[4][4] = {};
  for (int k0 = 0; k0 < 256; k0 += 64) {
#pragma unroll
    for (int p = 0; p < 8; ++p) {
      int flat = p * 256 + tid;
      int r = flat >> 4, cc = flat & 15;
      int m = m0 + r;
      int b = m >> tcShift, tc = m & tcMask;
      const float4 xv = *(const float4*)(x + (size_t)(b * 1024 + t0 + tc) * 256 + k0 + cc * 4);
      uint2 w2 = make_uint2(pack2(xv.x, xv.y), pack2(xv.z, xv.w));
      *(uint2*)&Al[r * 72 + cc * 4] = w2;
    }
#pragma unroll
    for (int p = 0; p < 8; ++p) {
      int flat = p * 256 + tid;
      int r = flat >> 4, cc = flat & 15;
      uint2 w2 = *(const uint2*)(WxT + (size_t)(n0 + r) * 256 + k0 + cc * 4);
      *(uint2*)&Bl[r * 72 + cc * 4] = w2;
    }
    __syncthreads();
#pragma unroll
    for (int kk = 0; kk < 64; kk += 32) {
      f16x8 af[4], bfr[4];
#pragma unroll
      for (int i = 0; i < 4; ++i) {
        af[i]  = lds16(&Al[(wr * 64 + i * 16 + (lane & 15)) * 72 + kk + (lane >> 4) * 8]);
        bfr[i] = lds16(&Bl[(wc * 64 + i * 16 + (lane & 15)) * 72 + kk + (lane >> 4) * 8]);
      }
#pragma unroll
      for (int mi = 0; mi < 4; ++mi)
#pragma unroll
        for (int ni = 0; ni < 4; ++ni)
          acc[mi][ni] = __builtin_amdgcn_mfma_f32_16x16x32_f16(af[mi], bfr[ni], acc[mi][ni], 0, 0, 0);
    }
    __syncthreads();
  }
#pragma unroll
  for (int ni = 0; ni < 4; ++ni) {
    int n = n0 + wc * 64 + ni * 16 + (lane & 15);
    int g = n >> 8;
    const float* bp = (g == 0) ? bi : (g == 1) ? bf : (g == 2) ? bg : bo;
    float bias = bp[n & 255];
    const int nperm = (n & 255) * 4 + g;
#pragma unroll
    for (int mi = 0; mi < 4; ++mi) {
#pragma unroll
      for (int ri = 0; ri < 4; ++ri) {
        int m = m0 + wr * 64 + mi * 16 + (lane >> 4) * 4 + ri;
        gates[(size_t)m * 1024 + nperm] = f16bits(acc[mi][ni][ri] + bias);
      }
    }
  }
}

// ---------------- fused: rec(chunk ci) + proj-gemm(chunk ci+1) ---------------
// 256 blocks x 512 threads; each block needs ~130 KB LDS -> exactly 1 block/CU.
// Blocks 0..127  : persistent per-batch recurrence on gcur.
// Blocks 128..255: 128x256-tile MFMA GEMM producing gnxt (next chunk's gates).
// Disjoint buffers -> no intra-kernel sync needed; kernel boundary syncs chunks.
__global__ __launch_bounds__(512, 2) void lstm_fused(
    const u32* __restrict__ Whpp, const u16* __restrict__ gcur,
    u32* __restrict__ h16s, float* __restrict__ c_s,
    const float* __restrict__ Why, const float* __restrict__ by,
    float* __restrict__ out, int Tc, int last,
    const float* __restrict__ x, const u16* __restrict__ WxT,
    u16* __restrict__ gnxt, const float* __restrict__ bi,
    const float* __restrict__ bf, const float* __restrict__ bg,
    const float* __restrict__ bo, int t0n, int tcShift, int doGemm) {
  extern __shared__ unsigned char smem[];
  const int t = threadIdx.x;

  if (blockIdx.x < 128) {
    // ---------------- recurrence path ----------------
    uint4* ldsW = (uint4*)smem;                       // [16][512] uint4 = 131072 B
    u32*   hq   = (u32*)(smem + 131072);              // [2][4*40] u32   = 1280 B
    const int b = blockIdx.x;
    const int l = t & 63, q = l >> 4;
    const int us = (t >> 6) * 16 + (l & 15);          // unit-slot: units 2us,2us+1

    u32 wreg[192];
    const uint4* Wp4 = (const uint4*)Whpp;
#pragma unroll
    for (int i4 = 0; i4 < 64; ++i4) {
      uint4 v = Wp4[i4 * 512 + t];
      const int ug = i4 >> 3, pp = i4 & 7;
      if (pp < 6) {
        wreg[ug * 24 + pp * 4 + 0] = v.x;
        wreg[ug * 24 + pp * 4 + 1] = v.y;
        wreg[ug * 24 + pp * 4 + 2] = v.z;
        wreg[ug * 24 + pp * 4 + 3] = v.w;
      } else {
        ldsW[(ug * 2 + (pp - 6)) * 512 + t] = v;
      }
    }
    if (t < 128) hq[(t >> 5) * 40 + (t & 31)] = h16s[b * 128 + t];
    float c0 = c_s[b * 256 + us * 2];
    float c1 = c_s[b * 256 + us * 2 + 1];
    const u16* gxp = gcur + (size_t)b * Tc * 1024 + us * 8;
    uint4 pre = *(const uint4*)gxp;
    int buf = 0;
    __syncthreads();

    for (int tc = 0; tc < Tc; ++tc) {
      // ---- issue phase: h first (critical path), then step-invariant weights
      const uint4* hb = (const uint4*)(hq + buf * 160 + q * 40);
      uint4 hv[8];
#pragma unroll
      for (int u = 0; u < 8; ++u) hv[u] = hb[u];
      uint4 wl6[8];
#pragma unroll
      for (int ug = 0; ug < 8; ++ug) wl6[ug] = ldsW[(ug * 2) * 512 + t];
      const uint4 gx = pre;
      if (tc + 1 < Tc) pre = *(const uint4*)(gxp + (size_t)(tc + 1) * 1024);
      // ---- register-weight dots (overlap wl6/wl7 LDS traffic)
      float acc[8];
#pragma unroll
      for (int i = 0; i < 8; ++i) acc[i] = 0.0f;
#pragma unroll
      for (int pp = 0; pp < 6; ++pp) {
        uint4 h4 = hv[pp];
#pragma unroll
        for (int ug = 0; ug < 8; ++ug) {
          acc[ug] = fdot2a(h4.x, wreg[ug * 24 + pp * 4 + 0], acc[ug]);
          acc[ug] = fdot2a(h4.y, wreg[ug * 24 + pp * 4 + 1], acc[ug]);
          acc[ug] = fdot2a(h4.z, wreg[ug * 24 + pp * 4 + 2], acc[ug]);
          acc[ug] = fdot2a(h4.w, wreg[ug * 24 + pp * 4 + 3], acc[ug]);
        }
      }
      uint4 wl7[8];
#pragma unroll
      for (int ug = 0; ug < 8; ++ug) wl7[ug] = ldsW[(ug * 2 + 1) * 512 + t];
      {
        uint4 h6 = hv[6];
#pragma unroll
        for (int ug = 0; ug < 8; ++ug) {
          acc[ug] = fdot2a(h6.x, wl6[ug].x, acc[ug]);
          acc[ug] = fdot2a(h6.y, wl6[ug].y, acc[ug]);
          acc[ug] = fdot2a(h6.z, wl6[ug].z, acc[ug]);
          acc[ug] = fdot2a(h6.w, wl6[ug].w, acc[ug]);
        }
        uint4 h7 = hv[7];
#pragma unroll
        for (int ug = 0; ug < 8; ++ug) {
          acc[ug] = fdot2a(h7.x, wl7[ug].x, acc[ug]);
          acc[ug] = fdot2a(h7.y, wl7[ug].y, acc[ug]);
          acc[ug] = fdot2a(h7.z, wl7[ug].z, acc[ug]);
          acc[ug] = fdot2a(h7.w, wl7[ug].w, acc[ug]);
        }
      }
#pragma unroll
      for (int i = 0; i < 8; ++i) acc[i] = qreduce(acc[i]);
      float zi0 = acc[0] + h2f((u16)(gx.x & 0xffff));
      float zf0 = acc[1] + h2f((u16)(gx.x >> 16));
      float zg0 = acc[2] + h2f((u16)(gx.y & 0xffff));
      float zo0 = acc[3] + h2f((u16)(gx.y >> 16));
      float zi1 = acc[4] + h2f((u16)(gx.z & 0xffff));
      float zf1 = acc[5] + h2f((u16)(gx.z >> 16));
      float zg1 = acc[6] + h2f((u16)(gx.w & 0xffff));
      float zo1 = acc[7] + h2f((u16)(gx.w >> 16));
      float i0 = sigmoidf_(zi0), f0 = sigmoidf_(zf0), g0 = tanhf_(zg0), o0 = sigmoidf_(zo0);
      float i1 = sigmoidf_(zi1), f1 = sigmoidf_(zf1), g1 = tanhf_(zg1), o1 = sigmoidf_(zo1);
      c0 = f0 * c0 + i0 * g0;
      c1 = f1 * c1 + i1 * g1;
      float h0 = o0 * tanhf_(c0);
      float h1 = o1 * tanhf_(c1);
      if (l < 16) {
        hq[(buf ^ 1) * 160 + (us >> 5) * 40 + (us & 31)] = pack2(h0, h1);
      }
      buf ^= 1;
      __syncthreads();
    }

    if (t < 128) h16s[b * 128 + t] = hq[buf * 160 + (t >> 5) * 40 + (t & 31)];
    if (l < 16) {
      c_s[b * 256 + us * 2]     = c0;
      c_s[b * 256 + us * 2 + 1] = c1;
    }
    if (last && t < 128) {                  // y = h_T @ W_hy + b_y
      float acc = by[t];
      const u16* hh = (const u16*)(hq + buf * 160);
#pragma unroll 8
      for (int k = 0; k < 256; ++k) {
        float hv = h2f(hh[((k >> 6) * 40 + ((k >> 1) & 31)) * 2 + (k & 1)]);
        acc += hv * Why[k * 128 + t];
      }
      out[b * 128 + t] = acc;
    }
    return;
  }

  // ---------------- GEMM path: gates for chunk ci+1 ----------------
  if (!doGemm) return;
  u16* Al = (u16*)smem;                     // [128][72] f16 = 18432 B
  u16* Bl = (u16*)(smem + 18432);           // [256][72] f16 = 36864 B
  const int gb = blockIdx.x - 128;
  const int lane = t & 63, wv = t >> 6;
  const int wr = wv >> 2, wc = wv & 3;      // 2x4 wave grid -> 128x256 tile
  const int tcMask = (1 << tcShift) - 1;
  const int ntiles = Tc * 4;
  for (int tt = gb; tt < ntiles; tt += 128) {
    const int m0 = (tt >> 2) * 128, n0 = (tt & 3) * 256;
    f32x4 acc[4][4] = {};
    for (int k0 = 0; k0 < 256; k0 += 64) {
#pragma unroll
      for (int p = 0; p < 2; ++p) {         // stage A: 128x64 f32 -> f16
        int flat = p * 512 + t;
        int r = flat >> 3, cc = flat & 7;
        int m = m0 + r;
        int b = m >> tcShift, tcl = m & tcMask;
        const float* src = x + (size_t)(b * 1024 + t0n + tcl) * 256 + k0 + cc * 8;
        const float4 xv0 = *(const float4*)src;
        const float4 xv1 = *(const float4*)(src + 4);
        uint4 w4;
        w4.x = pack2(xv0.x, xv0.y); w4.y = pack2(xv0.z, xv0.w);
        w4.z = pack2(xv1.x, xv1.y); w4.w = pack2(xv1.z, xv1.w);
        *(uint4*)&Al[r * 72 + cc * 8] = w4;
      }
#pragma unroll
      for (int p = 0; p < 4; ++p) {         // stage B: 256x64 f16
        int flat = p * 512 + t;
        int r = flat >> 3, cc = flat & 7;
        uint4 w4 = *(const uint4*)(WxT + (size_t)(n0 + r) * 256 + k0 + cc * 8);
        *(uint4*)&Bl[r * 72 + cc * 8] = w4;
      }
      __syncthreads();
#pragma unroll
      for (int kk = 0; kk < 64; kk += 32) {
        f16x8 af[4], bfr[4];
#pragma unroll
        for (int i = 0; i < 4; ++i) {
          af[i]  = lds16(&Al[(wr * 64 + i * 16 + (lane & 15)) * 72 + kk + (lane >> 4) * 8]);
          bfr[i] = lds16(&Bl[(wc * 64 + i * 16 + (lane & 15)) * 72 + kk + (lane >> 4) * 8]);
        }
#pragma unroll
        for (int mi = 0; mi < 4; ++mi)
#pragma unroll
          for (int ni = 0; ni < 4; ++ni)
            acc[mi][ni] = __builtin_amdgcn_mfma_f32_16x16x32_f16(af[mi], bfr[ni], acc[mi][ni], 0, 0, 0);
      }
      __syncthreads();
    }
#pragma unroll
    for (int ni = 0; ni < 4; ++ni) {
      int n = n0 + wc * 64 + ni * 16 + (lane & 15);
      int g = n >> 8;
      const float* bp = (g == 0) ? bi : (g == 1) ? bf : (g == 2) ? bg : bo;
      float bias = bp[n & 255];
      const int nperm = (n & 255) * 4 + g;
#pragma unroll
      for (int mi = 0; mi < 4; ++mi) {
#pragma unroll
        for (int ri = 0; ri < 4; ++ri) {
          int m = m0 + wr * 64 + mi * 16 + (lane >> 4) * 4 + ri;
          gnxt[(size_t)m * 1024 + nperm] = f16bits(acc[mi][ni][ri] + bias);
        }
      }
    }
  }
}

extern "C" void kernel_launch(void* const* d_in, const int* in_sizes, int n_in,
                              void* d_out, int out_size, void* d_ws, size_t ws_size,
                              hipStream_t stream) {
  const float* x   = (const float*)d_in[0];
  const float* Wxi = (const float*)d_in[1];
  const float* Whi = (const float*)d_in[2];
  const float* b_i = (const float*)d_in[3];
  const float* Wxf = (const float*)d_in[4];
  const float* Whf = (const float*)d_in[5];
  const float* b_f = (const float*)d_in[6];
  const float* Wxg = (const float*)d_in[7];
  const float* Whg = (const float*)d_in[8];
  const float* b_g = (const float*)d_in[9];
  const float* Wxo = (const float*)d_in[10];
  const float* Who = (const float*)d_in[11];
  const float* b_o = (const float*)d_in[12];
  const float* Why = (const float*)d_in[13];
  const float* b_y = (const float*)d_in[14];
  float* out = (float*)d_out;

  // choose T-chunk: 2 ping-pong gate buffers + tables must fit the workspace
  int Tc = 256;
  while (Tc > 32 && 2ull * ((size_t)128 * Tc * 1024 * 2) + 1245184ull > ws_size) Tc >>= 1;
  const int tcShift = __builtin_ctz((unsigned)Tc);
  const int nch = 1024 / Tc;

  char* wsb = (char*)d_ws;
  const size_t gbytes = (size_t)128 * Tc * 1024 * 2;
  u16*   gatesA = (u16*)wsb;
  u16*   gatesB = (u16*)(wsb + gbytes);
  u16*   WxT    = (u16*)(wsb + 2 * gbytes);
  u32*   Whpp   = (u32*)(wsb + 2 * gbytes + 524288);
  u32*   h16s   = (u32*)(wsb + 2 * gbytes + 1048576);
  float* c_s    = (float*)(wsb + 2 * gbytes + 1048576 + 65536);

  const int recLds = 131072 + 1280;
  (void)hipFuncSetAttribute((const void*)lstm_fused,
                            hipFuncAttributeMaxDynamicSharedMemorySize, recLds);

  lstm_prep<<<1728, 256, 0, stream>>>(Wxi, Wxf, Wxg, Wxo, Whi, Whf, Whg, Who,
                                      WxT, Whpp, h16s, c_s);
  // prologue: chunk 0 gates
  proj_gemm<<<dim3(Tc, 8), 256, 0, stream>>>(x, WxT, gatesA, b_i, b_f, b_g, b_o,
                                             0, tcShift);
  for (int ci = 0; ci < nch; ++ci) {
    u16* gcur = (ci & 1) ? gatesB : gatesA;
    u16* gnxt = (ci & 1) ? gatesA : gatesB;
    const int lastc = (ci == nch - 1) ? 1 : 0;
    lstm_fused<<<256, 512, recLds, stream>>>(
        Whpp, gcur, h16s, c_s, Why, b_y, out, Tc, lastc,
        x, WxT, gnxt, b_i, b_f, b_g, b_o, (ci + 1) * Tc, tcShift, lastc ? 0 : 1);
  }
}